// Round 1
// baseline (2442.718 us; speedup 1.0000x reference)
//
#include <hip/hip_runtime.h>
#include <hip/hip_bf16.h>
#include <math.h>

#define NN   100000
#define EE   200000
#define KK   4
#define DEG  8
#define FEAT 256
#define RANK 64
#define HID  512
#define OUTD 128

// num = DEG^(1/K) = 8^0.25 ; coef = num / (K-1)! = num/6
#define NUMF  1.6817928305074290861f
#define COEF  0.28029880508457151435f

// ---------------------------------------------------------------------------
// Fused node network: per 16-row tile compute
//   scaled = NUM * (emb @ Wp + bp)           [N,64]
//   emb2   = relu(emb @ W1 + b1) @ W2 + b2   [N,128]
// LDS: emb tile (16x260 padded) + hid tile (16x516 padded) = 49.7 KB
// ---------------------------------------------------------------------------
__global__ __launch_bounds__(256) void node_net(
    const float* __restrict__ emb,
    const float* __restrict__ Wp, const float* __restrict__ bp,
    const float* __restrict__ W1, const float* __restrict__ b1,
    const float* __restrict__ W2, const float* __restrict__ b2,
    float* __restrict__ scaled, float* __restrict__ emb2)
{
    __shared__ float s_emb[16][260];   // pad 256->260: rows land on banks 4r -> 2-way max (free)
    __shared__ float s_hid[16][516];   // pad 512->516: same trick

    const int t    = threadIdx.x;
    const int row0 = blockIdx.x * 16;

    // ---- load 16x256 emb tile (1024 float4, 4 per thread) ----
    for (int i = t; i < 16 * 64; i += 256) {
        int r  = i >> 6;
        int c4 = i & 63;
        float4 v = reinterpret_cast<const float4*>(emb + (size_t)(row0 + r) * FEAT)[c4];
        reinterpret_cast<float4*>(&s_emb[r][0])[c4] = v;
    }
    __syncthreads();

    const int r  = t >> 4;          // 0..15
    const int cc = (t & 15) * 4;    // 0..60

    // ---- stage 0: scaled = NUM*(emb@Wp + bp), 16x64 tile, 4 outs/thread ----
    {
        float a0 = 0.f, a1 = 0.f, a2 = 0.f, a3 = 0.f;
        for (int f = 0; f < FEAT; ++f) {
            float a  = s_emb[r][f];
            float4 w = *reinterpret_cast<const float4*>(Wp + (size_t)f * RANK + cc);
            a0 = fmaf(a, w.x, a0); a1 = fmaf(a, w.y, a1);
            a2 = fmaf(a, w.z, a2); a3 = fmaf(a, w.w, a3);
        }
        float4 bb = *reinterpret_cast<const float4*>(bp + cc);
        float4 o;
        o.x = NUMF * (a0 + bb.x); o.y = NUMF * (a1 + bb.y);
        o.z = NUMF * (a2 + bb.z); o.w = NUMF * (a3 + bb.w);
        *reinterpret_cast<float4*>(scaled + (size_t)(row0 + r) * RANK + cc) = o;
    }

    // ---- stage 1: hid = relu(emb@W1 + b1), in 8 chunks of 64 cols ----
    for (int hc = 0; hc < HID; hc += 64) {
        float a0 = 0.f, a1 = 0.f, a2 = 0.f, a3 = 0.f;
        for (int f = 0; f < FEAT; ++f) {
            float a  = s_emb[r][f];
            float4 w = *reinterpret_cast<const float4*>(W1 + (size_t)f * HID + hc + cc);
            a0 = fmaf(a, w.x, a0); a1 = fmaf(a, w.y, a1);
            a2 = fmaf(a, w.z, a2); a3 = fmaf(a, w.w, a3);
        }
        float4 bb = *reinterpret_cast<const float4*>(b1 + hc + cc);
        float4 o;
        o.x = fmaxf(a0 + bb.x, 0.f); o.y = fmaxf(a1 + bb.y, 0.f);
        o.z = fmaxf(a2 + bb.z, 0.f); o.w = fmaxf(a3 + bb.w, 0.f);
        *reinterpret_cast<float4*>(&s_hid[r][hc + cc]) = o;
    }
    __syncthreads();

    // ---- stage 2: emb2 = hid @ W2 + b2, 16x128 tile, 8 outs/thread (2 rows x 4 cols) ----
    {
        const int r0 = (t >> 5) * 2;      // 0,2,..,14
        const int c  = (t & 31) * 4;      // 0..124
        float a00=0.f,a01=0.f,a02=0.f,a03=0.f;
        float a10=0.f,a11=0.f,a12=0.f,a13=0.f;
        for (int h = 0; h < HID; ++h) {
            float h0 = s_hid[r0][h];
            float h1 = s_hid[r0 + 1][h];
            float4 w = *reinterpret_cast<const float4*>(W2 + (size_t)h * OUTD + c);
            a00 = fmaf(h0, w.x, a00); a01 = fmaf(h0, w.y, a01);
            a02 = fmaf(h0, w.z, a02); a03 = fmaf(h0, w.w, a03);
            a10 = fmaf(h1, w.x, a10); a11 = fmaf(h1, w.y, a11);
            a12 = fmaf(h1, w.z, a12); a13 = fmaf(h1, w.w, a13);
        }
        float4 bb = *reinterpret_cast<const float4*>(b2 + c);
        float4 o0, o1;
        o0.x = a00 + bb.x; o0.y = a01 + bb.y; o0.z = a02 + bb.z; o0.w = a03 + bb.w;
        o1.x = a10 + bb.x; o1.y = a11 + bb.y; o1.z = a12 + bb.z; o1.w = a13 + bb.w;
        *reinterpret_cast<float4*>(emb2 + (size_t)(row0 + r0)     * OUTD + c) = o0;
        *reinterpret_cast<float4*>(emb2 + (size_t)(row0 + r0 + 1) * OUTD + c) = o1;
    }
}

// ---------------------------------------------------------------------------
// Edge network: one wave per edge. 32 edges per 256-thread block.
//   g_k[r] = scaled[node_k][r]; excl via exact pair products; term = tanh(COEF*excl)
//   q_out = term @ Wq (Wq in LDS); edge2 = relu(sum emb2 rows);
//   atomicAdd contrib into out accumulator.
// ---------------------------------------------------------------------------
__global__ __launch_bounds__(256) void edge_net(
    const float* __restrict__ scaled, const float* __restrict__ emb2,
    const float* __restrict__ Wq, const float* __restrict__ bq,
    const int* __restrict__ edge_nodes, float* __restrict__ out_acc)
{
    __shared__ float s_wq[RANK * OUTD];      // 32 KB
    __shared__ float s_term[4][64][4];       // [wave][r][k], 4 KB

    const int t = threadIdx.x;
    for (int i = t; i < RANK * OUTD / 4; i += 256)
        reinterpret_cast<float4*>(s_wq)[i] = reinterpret_cast<const float4*>(Wq)[i];
    __syncthreads();

    const int wave = t >> 6;
    const int lane = t & 63;
    const int c0 = lane, c1 = lane + 64;
    const float bq0 = bq[c0], bq1 = bq[c1];

    const int ebase = blockIdx.x * 32;
    for (int it = 0; it < 8; ++it) {
        const int e = ebase + it * 4 + wave;
        const int4 nd = *reinterpret_cast<const int4*>(edge_nodes + (size_t)e * KK);

        // gather scaled rows (coalesced: 64 lanes x 4B contiguous per node)
        float g0 = scaled[(size_t)nd.x * RANK + lane];
        float g1 = scaled[(size_t)nd.y * RANK + lane];
        float g2 = scaled[(size_t)nd.z * RANK + lane];
        float g3 = scaled[(size_t)nd.w * RANK + lane];

        float e01 = g0 * g1, e23 = g2 * g3;
        float t0 = tanhf(COEF * (g1 * e23));
        float t1 = tanhf(COEF * (g0 * e23));
        float t2 = tanhf(COEF * (e01 * g3));
        float t3 = tanhf(COEF * (e01 * g2));

        // stage term into LDS in A-broadcast layout [r][k] (wave-local, no barrier needed)
        *reinterpret_cast<float4*>(&s_term[wave][lane][0]) = make_float4(t0, t1, t2, t3);

        // q_out: [4 x 128] = term[4x64] @ Wq[64x128]; lane owns cols {lane, lane+64}
        float a00=0.f,a01=0.f,a10=0.f,a11=0.f,a20=0.f,a21=0.f,a30=0.f,a31=0.f;
        #pragma unroll 8
        for (int rr = 0; rr < 64; ++rr) {
            float4 tm = *reinterpret_cast<const float4*>(&s_term[wave][rr][0]); // broadcast
            float w0 = s_wq[rr * OUTD + c0];
            float w1 = s_wq[rr * OUTD + c1];
            a00 = fmaf(tm.x, w0, a00); a01 = fmaf(tm.x, w1, a01);
            a10 = fmaf(tm.y, w0, a10); a11 = fmaf(tm.y, w1, a11);
            a20 = fmaf(tm.z, w0, a20); a21 = fmaf(tm.z, w1, a21);
            a30 = fmaf(tm.w, w0, a30); a31 = fmaf(tm.w, w1, a31);
        }

        // edge2 = relu(sum of emb2 rows) (coalesced gathers)
        float s0 = emb2[(size_t)nd.x * OUTD + c0] + emb2[(size_t)nd.y * OUTD + c0]
                 + emb2[(size_t)nd.z * OUTD + c0] + emb2[(size_t)nd.w * OUTD + c0];
        float s1 = emb2[(size_t)nd.x * OUTD + c1] + emb2[(size_t)nd.y * OUTD + c1]
                 + emb2[(size_t)nd.z * OUTD + c1] + emb2[(size_t)nd.w * OUTD + c1];
        s0 = fmaxf(s0, 0.f) + bq0;
        s1 = fmaxf(s1, 0.f) + bq1;

        atomicAdd(out_acc + (size_t)nd.x * OUTD + c0, a00 + s0);
        atomicAdd(out_acc + (size_t)nd.x * OUTD + c1, a01 + s1);
        atomicAdd(out_acc + (size_t)nd.y * OUTD + c0, a10 + s0);
        atomicAdd(out_acc + (size_t)nd.y * OUTD + c1, a11 + s1);
        atomicAdd(out_acc + (size_t)nd.z * OUTD + c0, a20 + s0);
        atomicAdd(out_acc + (size_t)nd.z * OUTD + c1, a21 + s1);
        atomicAdd(out_acc + (size_t)nd.w * OUTD + c0, a30 + s0);
        atomicAdd(out_acc + (size_t)nd.w * OUTD + c1, a31 + s1);
    }
}

// ---------------------------------------------------------------------------
// Finalize: out = relu(out / DEG), in place, vectorized
// ---------------------------------------------------------------------------
__global__ __launch_bounds__(256) void finalize_k(float* __restrict__ out, int n4)
{
    int i = blockIdx.x * 256 + threadIdx.x;
    if (i < n4) {
        float4 v = reinterpret_cast<float4*>(out)[i];
        v.x = fmaxf(v.x * 0.125f, 0.f);
        v.y = fmaxf(v.y * 0.125f, 0.f);
        v.z = fmaxf(v.z * 0.125f, 0.f);
        v.w = fmaxf(v.w * 0.125f, 0.f);
        reinterpret_cast<float4*>(out)[i] = v;
    }
}

extern "C" void kernel_launch(void* const* d_in, const int* in_sizes, int n_in,
                              void* d_out, int out_size, void* d_ws, size_t ws_size,
                              hipStream_t stream)
{
    const float* emb = (const float*)d_in[0];
    const float* Wp  = (const float*)d_in[1];
    const float* bp  = (const float*)d_in[2];
    const float* Wq  = (const float*)d_in[3];
    const float* bq  = (const float*)d_in[4];
    const float* W1  = (const float*)d_in[5];
    const float* b1  = (const float*)d_in[6];
    const float* W2  = (const float*)d_in[7];
    const float* b2  = (const float*)d_in[8];
    const int* edge_nodes = (const int*)d_in[9];
    float* out = (float*)d_out;

    float* scaled = (float*)d_ws;                      // N*RANK  = 25.6 MB
    float* emb2   = scaled + (size_t)NN * RANK;        // N*OUTD  = 51.2 MB

    hipMemsetAsync(d_out, 0, (size_t)NN * OUTD * sizeof(float), stream);

    node_net<<<NN / 16, 256, 0, stream>>>(emb, Wp, bp, W1, b1, W2, b2, scaled, emb2);
    edge_net<<<EE / 32, 256, 0, stream>>>(scaled, emb2, Wq, bq, edge_nodes, out);
    finalize_k<<<(NN * OUTD / 4 + 255) / 256, 256, 0, stream>>>(out, NN * OUTD / 4);
}

// Round 2
// 657.578 us; speedup vs baseline: 3.7147x; 3.7147x over previous
//
#include <hip/hip_runtime.h>
#include <hip/hip_bf16.h>
#include <math.h>

#define NN   100000
#define EE   200000
#define KK   4
#define DEG  8
#define FEAT 256
#define RANK 64
#define HID  512
#define OUTD 128

// num = DEG^(1/K) = 8^0.25 ; coef = num / (K-1)! = num/6
#define NUMF  1.6817928305074290861f
#define COEF  0.28029880508457151435f

typedef __attribute__((ext_vector_type(8))) short short8;
typedef __attribute__((ext_vector_type(4))) float float4v;

__device__ __forceinline__ short f2bf(float x) {
    union { float f; unsigned u; } v; v.f = x;
    unsigned r = v.u + 0x7fff + ((v.u >> 16) & 1);   // RNE
    return (short)(r >> 16);
}

// ---------------------------------------------------------------------------
// Pack Wp/W1/W2 (fp32 row-major [K x N]) into bf16 MFMA B-fragment order:
// tile (nt,kt) of 32(k) x 16(n); lane l holds B[kt*32 + (l>>4)*8 + j][nt*16 + (l&15)]
// stored at dst[((t_local*64 + l)*8 + j] with t_local = nt*KT + kt.
// ---------------------------------------------------------------------------
__global__ __launch_bounds__(256) void pack_w(
    const float* __restrict__ Wp, const float* __restrict__ W1,
    const float* __restrict__ W2,
    short* __restrict__ bWp, short* __restrict__ bW1, short* __restrict__ bW2)
{
    int g = blockIdx.x * 256 + threadIdx.x;   // 104 blocks * 256 = 26624 = (32+256+128)*64
    int tile = g >> 6, l = g & 63;
    int lm = l & 15, lq = l >> 4;
    const float* src; short* dst; int N, kt, nt, tl;
    if (tile < 32)       { tl = tile;        nt = tl >> 3; kt = tl & 7;  src = Wp; dst = bWp; N = RANK; }
    else if (tile < 288) { tl = tile - 32;   nt = tl >> 3; kt = tl & 7;  src = W1; dst = bW1; N = HID;  }
    else                 { tl = tile - 288;  nt = tl >> 4; kt = tl & 15; src = W2; dst = bW2; N = OUTD; }
    short8 pk;
    #pragma unroll
    for (int j = 0; j < 8; ++j)
        pk[j] = f2bf(src[(size_t)(kt * 32 + lq * 8 + j) * N + nt * 16 + lm]);
    *reinterpret_cast<short8*>(dst + (size_t)(tl * 64 + l) * 8) = pk;
}

// ---------------------------------------------------------------------------
// Fused node network on MFMA (bf16 in, fp32 acc):
//   scaled = NUM * (emb @ Wp + bp)           [N,64]
//   hid    = relu(emb @ W1 + b1)  (LDS bf16) [32,512] per block
//   emb2   = hid @ W2 + b2                   [N,128]
// 32 rows/block, 4 waves. A-frag: lane l -> A[m=l&15][k=(l>>4)*8+j] (ds_read_b128,
// row stride padded so rows start 4 banks apart -> 2-way = free).
// ---------------------------------------------------------------------------
__global__ __launch_bounds__(256) void node_net_mfma(
    const float* __restrict__ emb,
    const short8* __restrict__ bWp, const float* __restrict__ bp,
    const short8* __restrict__ bW1, const float* __restrict__ b1,
    const short8* __restrict__ bW2, const float* __restrict__ b2,
    float* __restrict__ scaled, float* __restrict__ emb2)
{
    __shared__ short s_a[32][264];   // 256 + 8 pad (16B-aligned rows, 528B stride)
    __shared__ short s_h[32][520];   // 512 + 8 pad (1040B stride)

    const int t = threadIdx.x;
    const int w = t >> 6, l = t & 63;
    const int lm = l & 15, lq = l >> 4;
    const int row0 = blockIdx.x * 32;

    // ---- load 32x256 emb tile, convert fp32 -> bf16 into LDS ----
    for (int i = t; i < 32 * 32; i += 256) {        // 8 floats per item
        int r = i >> 5, c8 = (i & 31) * 8;
        const float4* src = reinterpret_cast<const float4*>(emb + (size_t)(row0 + r) * FEAT + c8);
        float4 v0 = src[0], v1 = src[1];
        short8 pk;
        pk[0] = f2bf(v0.x); pk[1] = f2bf(v0.y); pk[2] = f2bf(v0.z); pk[3] = f2bf(v0.w);
        pk[4] = f2bf(v1.x); pk[5] = f2bf(v1.y); pk[6] = f2bf(v1.z); pk[7] = f2bf(v1.w);
        *reinterpret_cast<short8*>(&s_a[r][c8]) = pk;
    }
    __syncthreads();

    // ---- stage p: scaled = NUM*(emb@Wp + bp); wave w owns cols [w*16, w*16+16) ----
    {
        float4v acc0 = {0.f, 0.f, 0.f, 0.f}, acc1 = {0.f, 0.f, 0.f, 0.f};
        #pragma unroll
        for (int kt = 0; kt < 8; ++kt) {
            short8 a0 = *reinterpret_cast<const short8*>(&s_a[lm][kt * 32 + lq * 8]);
            short8 a1 = *reinterpret_cast<const short8*>(&s_a[16 + lm][kt * 32 + lq * 8]);
            short8 b  = bWp[(w * 8 + kt) * 64 + l];
            acc0 = __builtin_amdgcn_mfma_f32_16x16x32_bf16(a0, b, acc0, 0, 0, 0);
            acc1 = __builtin_amdgcn_mfma_f32_16x16x32_bf16(a1, b, acc1, 0, 0, 0);
        }
        const int col = w * 16 + lm;
        const float bpv = bp[col];
        #pragma unroll
        for (int rr = 0; rr < 4; ++rr) {
            scaled[(size_t)(row0 + lq * 4 + rr) * RANK + col]      = NUMF * (acc0[rr] + bpv);
            scaled[(size_t)(row0 + 16 + lq * 4 + rr) * RANK + col] = NUMF * (acc1[rr] + bpv);
        }
    }

    // ---- stage 1: hid = relu(emb@W1 + b1) -> LDS bf16; wave w owns cols [w*128, +128) ----
    {
        float4v acc[2][8];
        #pragma unroll
        for (int mt = 0; mt < 2; ++mt)
            #pragma unroll
            for (int n8 = 0; n8 < 8; ++n8)
                acc[mt][n8] = (float4v){0.f, 0.f, 0.f, 0.f};

        for (int kt = 0; kt < 8; ++kt) {
            short8 a0 = *reinterpret_cast<const short8*>(&s_a[lm][kt * 32 + lq * 8]);
            short8 a1 = *reinterpret_cast<const short8*>(&s_a[16 + lm][kt * 32 + lq * 8]);
            #pragma unroll
            for (int n8 = 0; n8 < 8; ++n8) {
                short8 b = bW1[((w * 8 + n8) * 8 + kt) * 64 + l];
                acc[0][n8] = __builtin_amdgcn_mfma_f32_16x16x32_bf16(a0, b, acc[0][n8], 0, 0, 0);
                acc[1][n8] = __builtin_amdgcn_mfma_f32_16x16x32_bf16(a1, b, acc[1][n8], 0, 0, 0);
            }
        }
        #pragma unroll
        for (int n8 = 0; n8 < 8; ++n8) {
            const int col = w * 128 + n8 * 16 + lm;
            const float bb = b1[col];
            #pragma unroll
            for (int mt = 0; mt < 2; ++mt)
                #pragma unroll
                for (int rr = 0; rr < 4; ++rr)
                    s_h[mt * 16 + lq * 4 + rr][col] = f2bf(fmaxf(acc[mt][n8][rr] + bb, 0.f));
        }
    }
    __syncthreads();

    // ---- stage 2: emb2 = hid @ W2 + b2; wave w owns cols [w*32, +32) ----
    {
        float4v acc[2][2];
        #pragma unroll
        for (int mt = 0; mt < 2; ++mt)
            #pragma unroll
            for (int n2 = 0; n2 < 2; ++n2)
                acc[mt][n2] = (float4v){0.f, 0.f, 0.f, 0.f};

        for (int kt = 0; kt < 16; ++kt) {
            short8 a0 = *reinterpret_cast<const short8*>(&s_h[lm][kt * 32 + lq * 8]);
            short8 a1 = *reinterpret_cast<const short8*>(&s_h[16 + lm][kt * 32 + lq * 8]);
            #pragma unroll
            for (int n2 = 0; n2 < 2; ++n2) {
                short8 b = bW2[((w * 2 + n2) * 16 + kt) * 64 + l];
                acc[0][n2] = __builtin_amdgcn_mfma_f32_16x16x32_bf16(a0, b, acc[0][n2], 0, 0, 0);
                acc[1][n2] = __builtin_amdgcn_mfma_f32_16x16x32_bf16(a1, b, acc[1][n2], 0, 0, 0);
            }
        }
        #pragma unroll
        for (int n2 = 0; n2 < 2; ++n2) {
            const int col = w * 32 + n2 * 16 + lm;
            const float bb = b2[col];
            #pragma unroll
            for (int mt = 0; mt < 2; ++mt)
                #pragma unroll
                for (int rr = 0; rr < 4; ++rr)
                    emb2[(size_t)(row0 + mt * 16 + lq * 4 + rr) * OUTD + col] = acc[mt][n2][rr] + bb;
        }
    }
}

// ---------------------------------------------------------------------------
// Edge network: one wave per edge (unchanged from round 1).
// ---------------------------------------------------------------------------
__global__ __launch_bounds__(256) void edge_net(
    const float* __restrict__ scaled, const float* __restrict__ emb2,
    const float* __restrict__ Wq, const float* __restrict__ bq,
    const int* __restrict__ edge_nodes, float* __restrict__ out_acc)
{
    __shared__ float s_wq[RANK * OUTD];      // 32 KB
    __shared__ float s_term[4][64][4];       // [wave][r][k], 4 KB

    const int t = threadIdx.x;
    for (int i = t; i < RANK * OUTD / 4; i += 256)
        reinterpret_cast<float4*>(s_wq)[i] = reinterpret_cast<const float4*>(Wq)[i];
    __syncthreads();

    const int wave = t >> 6;
    const int lane = t & 63;
    const int c0 = lane, c1 = lane + 64;
    const float bq0 = bq[c0], bq1 = bq[c1];

    const int ebase = blockIdx.x * 32;
    for (int it = 0; it < 8; ++it) {
        const int e = ebase + it * 4 + wave;
        const int4 nd = *reinterpret_cast<const int4*>(edge_nodes + (size_t)e * KK);

        float g0 = scaled[(size_t)nd.x * RANK + lane];
        float g1 = scaled[(size_t)nd.y * RANK + lane];
        float g2 = scaled[(size_t)nd.z * RANK + lane];
        float g3 = scaled[(size_t)nd.w * RANK + lane];

        float e01 = g0 * g1, e23 = g2 * g3;
        float t0 = tanhf(COEF * (g1 * e23));
        float t1 = tanhf(COEF * (g0 * e23));
        float t2 = tanhf(COEF * (e01 * g3));
        float t3 = tanhf(COEF * (e01 * g2));

        *reinterpret_cast<float4*>(&s_term[wave][lane][0]) = make_float4(t0, t1, t2, t3);

        float a00=0.f,a01=0.f,a10=0.f,a11=0.f,a20=0.f,a21=0.f,a30=0.f,a31=0.f;
        #pragma unroll 8
        for (int rr = 0; rr < 64; ++rr) {
            float4 tm = *reinterpret_cast<const float4*>(&s_term[wave][rr][0]); // broadcast
            float w0 = s_wq[rr * OUTD + c0];
            float w1 = s_wq[rr * OUTD + c1];
            a00 = fmaf(tm.x, w0, a00); a01 = fmaf(tm.x, w1, a01);
            a10 = fmaf(tm.y, w0, a10); a11 = fmaf(tm.y, w1, a11);
            a20 = fmaf(tm.z, w0, a20); a21 = fmaf(tm.z, w1, a21);
            a30 = fmaf(tm.w, w0, a30); a31 = fmaf(tm.w, w1, a31);
        }

        float s0 = emb2[(size_t)nd.x * OUTD + c0] + emb2[(size_t)nd.y * OUTD + c0]
                 + emb2[(size_t)nd.z * OUTD + c0] + emb2[(size_t)nd.w * OUTD + c0];
        float s1 = emb2[(size_t)nd.x * OUTD + c1] + emb2[(size_t)nd.y * OUTD + c1]
                 + emb2[(size_t)nd.z * OUTD + c1] + emb2[(size_t)nd.w * OUTD + c1];
        s0 = fmaxf(s0, 0.f) + bq0;
        s1 = fmaxf(s1, 0.f) + bq1;

        atomicAdd(out_acc + (size_t)nd.x * OUTD + c0, a00 + s0);
        atomicAdd(out_acc + (size_t)nd.x * OUTD + c1, a01 + s1);
        atomicAdd(out_acc + (size_t)nd.y * OUTD + c0, a10 + s0);
        atomicAdd(out_acc + (size_t)nd.y * OUTD + c1, a11 + s1);
        atomicAdd(out_acc + (size_t)nd.z * OUTD + c0, a20 + s0);
        atomicAdd(out_acc + (size_t)nd.z * OUTD + c1, a21 + s1);
        atomicAdd(out_acc + (size_t)nd.w * OUTD + c0, a30 + s0);
        atomicAdd(out_acc + (size_t)nd.w * OUTD + c1, a31 + s1);
    }
}

// ---------------------------------------------------------------------------
// Finalize: out = relu(out / DEG), in place
// ---------------------------------------------------------------------------
__global__ __launch_bounds__(256) void finalize_k(float* __restrict__ out, int n4)
{
    int i = blockIdx.x * 256 + threadIdx.x;
    if (i < n4) {
        float4 v = reinterpret_cast<float4*>(out)[i];
        v.x = fmaxf(v.x * 0.125f, 0.f);
        v.y = fmaxf(v.y * 0.125f, 0.f);
        v.z = fmaxf(v.z * 0.125f, 0.f);
        v.w = fmaxf(v.w * 0.125f, 0.f);
        reinterpret_cast<float4*>(out)[i] = v;
    }
}

extern "C" void kernel_launch(void* const* d_in, const int* in_sizes, int n_in,
                              void* d_out, int out_size, void* d_ws, size_t ws_size,
                              hipStream_t stream)
{
    const float* emb = (const float*)d_in[0];
    const float* Wp  = (const float*)d_in[1];
    const float* bp  = (const float*)d_in[2];
    const float* Wq  = (const float*)d_in[3];
    const float* bq  = (const float*)d_in[4];
    const float* W1  = (const float*)d_in[5];
    const float* b1  = (const float*)d_in[6];
    const float* W2  = (const float*)d_in[7];
    const float* b2  = (const float*)d_in[8];
    const int* edge_nodes = (const int*)d_in[9];
    float* out = (float*)d_out;

    float* scaled = (float*)d_ws;                      // N*RANK fp32 = 25.6 MB
    float* emb2v  = scaled + (size_t)NN * RANK;        // N*OUTD fp32 = 51.2 MB
    short* bWp = (short*)(emb2v + (size_t)NN * OUTD);  // 16K bf16
    short* bW1 = bWp + 256 * 64;                       // 128K bf16
    short* bW2 = bW1 + 256 * 512;                      // 64K bf16

    hipMemsetAsync(d_out, 0, (size_t)NN * OUTD * sizeof(float), stream);

    pack_w<<<104, 256, 0, stream>>>(Wp, W1, W2, bWp, bW1, bW2);
    node_net_mfma<<<NN / 32, 256, 0, stream>>>(
        emb, (const short8*)bWp, bp, (const short8*)bW1, b1, (const short8*)bW2, b2,
        scaled, emb2v);
    edge_net<<<EE / 32, 256, 0, stream>>>(scaled, emb2v, Wq, bq, edge_nodes, out);
    finalize_k<<<(NN * OUTD / 4 + 255) / 256, 256, 0, stream>>>(out, NN * OUTD / 4);
}

// Round 3
// 630.221 us; speedup vs baseline: 3.8760x; 1.0434x over previous
//
#include <hip/hip_runtime.h>
#include <hip/hip_bf16.h>
#include <math.h>

#define NN   100000
#define EE   200000
#define KK   4
#define DEG  8
#define FEAT 256
#define RANK 64
#define HID  512
#define OUTD 128
#define EPB  25000   // edges per permutation block = NN/KK

// num = DEG^(1/K) = 8^0.25 ; coef = num / (K-1)! = num/6
#define NUMF  1.6817928305074290861f
#define COEF  0.28029880508457151435f

typedef __attribute__((ext_vector_type(8))) short short8;
typedef __attribute__((ext_vector_type(4))) float float4v;

__device__ __forceinline__ short f2bf(float x) {
    union { float f; unsigned u; } v; v.f = x;
    unsigned r = v.u + 0x7fff + ((v.u >> 16) & 1);   // RNE
    return (short)(r >> 16);
}
__device__ __forceinline__ float bf2f(short u) {
    union { unsigned u; float f; } v;
    v.u = ((unsigned)(unsigned short)u) << 16;
    return v.f;
}

// ---------------------------------------------------------------------------
// Pack Wp/W1/W2 (fp32 row-major [K x N]) into bf16 MFMA B-fragment order.
// ---------------------------------------------------------------------------
__global__ __launch_bounds__(256) void pack_w(
    const float* __restrict__ Wp, const float* __restrict__ W1,
    const float* __restrict__ W2,
    short* __restrict__ bWp, short* __restrict__ bW1, short* __restrict__ bW2)
{
    int g = blockIdx.x * 256 + threadIdx.x;   // 104 blocks * 256 = (32+256+128)*64
    int tile = g >> 6, l = g & 63;
    int lm = l & 15, lq = l >> 4;
    const float* src; short* dst; int N, kt, nt, tl;
    if (tile < 32)       { tl = tile;        nt = tl >> 3; kt = tl & 7;  src = Wp; dst = bWp; N = RANK; }
    else if (tile < 288) { tl = tile - 32;   nt = tl >> 3; kt = tl & 7;  src = W1; dst = bW1; N = HID;  }
    else                 { tl = tile - 288;  nt = tl >> 4; kt = tl & 15; src = W2; dst = bW2; N = OUTD; }
    short8 pk;
    #pragma unroll
    for (int j = 0; j < 8; ++j)
        pk[j] = f2bf(src[(size_t)(kt * 32 + lq * 8 + j) * N + nt * 16 + lm]);
    *reinterpret_cast<short8*>(dst + (size_t)(tl * 64 + l) * 8) = pk;
}

// ---------------------------------------------------------------------------
// Fused node network on MFMA (bf16 in, fp32 acc), bf16 outputs:
//   scaled_b = bf16( NUM * (emb @ Wp + bp) )   [N,64]
//   emb2_b   = bf16( relu(emb@W1+b1) @ W2+b2 ) [N,128]
// ---------------------------------------------------------------------------
__global__ __launch_bounds__(256) void node_net_mfma(
    const float* __restrict__ emb,
    const short8* __restrict__ bWp, const float* __restrict__ bp,
    const short8* __restrict__ bW1, const float* __restrict__ b1,
    const short8* __restrict__ bW2, const float* __restrict__ b2,
    short* __restrict__ scaled_b, short* __restrict__ emb2_b)
{
    __shared__ short s_a[32][264];
    __shared__ short s_h[32][520];

    const int t = threadIdx.x;
    const int w = t >> 6, l = t & 63;
    const int lm = l & 15, lq = l >> 4;
    const int row0 = blockIdx.x * 32;

    for (int i = t; i < 32 * 32; i += 256) {
        int r = i >> 5, c8 = (i & 31) * 8;
        const float4* src = reinterpret_cast<const float4*>(emb + (size_t)(row0 + r) * FEAT + c8);
        float4 v0 = src[0], v1 = src[1];
        short8 pk;
        pk[0] = f2bf(v0.x); pk[1] = f2bf(v0.y); pk[2] = f2bf(v0.z); pk[3] = f2bf(v0.w);
        pk[4] = f2bf(v1.x); pk[5] = f2bf(v1.y); pk[6] = f2bf(v1.z); pk[7] = f2bf(v1.w);
        *reinterpret_cast<short8*>(&s_a[r][c8]) = pk;
    }
    __syncthreads();

    // ---- stage p: scaled ----
    {
        float4v acc0 = {0.f, 0.f, 0.f, 0.f}, acc1 = {0.f, 0.f, 0.f, 0.f};
        #pragma unroll
        for (int kt = 0; kt < 8; ++kt) {
            short8 a0 = *reinterpret_cast<const short8*>(&s_a[lm][kt * 32 + lq * 8]);
            short8 a1 = *reinterpret_cast<const short8*>(&s_a[16 + lm][kt * 32 + lq * 8]);
            short8 b  = bWp[(w * 8 + kt) * 64 + l];
            acc0 = __builtin_amdgcn_mfma_f32_16x16x32_bf16(a0, b, acc0, 0, 0, 0);
            acc1 = __builtin_amdgcn_mfma_f32_16x16x32_bf16(a1, b, acc1, 0, 0, 0);
        }
        const int col = w * 16 + lm;
        const float bpv = bp[col];
        #pragma unroll
        for (int rr = 0; rr < 4; ++rr) {
            scaled_b[(size_t)(row0 + lq * 4 + rr) * RANK + col]      = f2bf(NUMF * (acc0[rr] + bpv));
            scaled_b[(size_t)(row0 + 16 + lq * 4 + rr) * RANK + col] = f2bf(NUMF * (acc1[rr] + bpv));
        }
    }

    // ---- stage 1: hid = relu(emb@W1+b1) -> LDS bf16 ----
    {
        float4v acc[2][8];
        #pragma unroll
        for (int mt = 0; mt < 2; ++mt)
            #pragma unroll
            for (int n8 = 0; n8 < 8; ++n8)
                acc[mt][n8] = (float4v){0.f, 0.f, 0.f, 0.f};

        for (int kt = 0; kt < 8; ++kt) {
            short8 a0 = *reinterpret_cast<const short8*>(&s_a[lm][kt * 32 + lq * 8]);
            short8 a1 = *reinterpret_cast<const short8*>(&s_a[16 + lm][kt * 32 + lq * 8]);
            #pragma unroll
            for (int n8 = 0; n8 < 8; ++n8) {
                short8 b = bW1[((w * 8 + n8) * 8 + kt) * 64 + l];
                acc[0][n8] = __builtin_amdgcn_mfma_f32_16x16x32_bf16(a0, b, acc[0][n8], 0, 0, 0);
                acc[1][n8] = __builtin_amdgcn_mfma_f32_16x16x32_bf16(a1, b, acc[1][n8], 0, 0, 0);
            }
        }
        #pragma unroll
        for (int n8 = 0; n8 < 8; ++n8) {
            const int col = w * 128 + n8 * 16 + lm;
            const float bb = b1[col];
            #pragma unroll
            for (int mt = 0; mt < 2; ++mt)
                #pragma unroll
                for (int rr = 0; rr < 4; ++rr)
                    s_h[mt * 16 + lq * 4 + rr][col] = f2bf(fmaxf(acc[mt][n8][rr] + bb, 0.f));
        }
    }
    __syncthreads();

    // ---- stage 2: emb2 = hid @ W2 + b2 ----
    {
        float4v acc[2][2];
        #pragma unroll
        for (int mt = 0; mt < 2; ++mt)
            #pragma unroll
            for (int n2 = 0; n2 < 2; ++n2)
                acc[mt][n2] = (float4v){0.f, 0.f, 0.f, 0.f};

        for (int kt = 0; kt < 16; ++kt) {
            short8 a0 = *reinterpret_cast<const short8*>(&s_h[lm][kt * 32 + lq * 8]);
            short8 a1 = *reinterpret_cast<const short8*>(&s_h[16 + lm][kt * 32 + lq * 8]);
            #pragma unroll
            for (int n2 = 0; n2 < 2; ++n2) {
                short8 b = bW2[((w * 2 + n2) * 16 + kt) * 64 + l];
                acc[0][n2] = __builtin_amdgcn_mfma_f32_16x16x32_bf16(a0, b, acc[0][n2], 0, 0, 0);
                acc[1][n2] = __builtin_amdgcn_mfma_f32_16x16x32_bf16(a1, b, acc[1][n2], 0, 0, 0);
            }
        }
        #pragma unroll
        for (int n2 = 0; n2 < 2; ++n2) {
            const int col = w * 32 + n2 * 16 + lm;
            const float bb = b2[col];
            #pragma unroll
            for (int mt = 0; mt < 2; ++mt)
                #pragma unroll
                for (int rr = 0; rr < 4; ++rr)
                    emb2_b[(size_t)(row0 + mt * 16 + lq * 4 + rr) * OUTD + col] =
                        f2bf(acc[mt][n2][rr] + bb);
        }
    }
}

// ---------------------------------------------------------------------------
// Inverse incidence index: node n appears exactly once per permutation block d.
// inv[n*8 + d] = e*4 + k. No atomics (exactly one writer per cell).
// ---------------------------------------------------------------------------
__global__ __launch_bounds__(256) void make_inv(
    const int* __restrict__ edge_nodes, int* __restrict__ inv)
{
    int i = blockIdx.x * 256 + threadIdx.x;          // < EE*KK = 800000
    int node = edge_nodes[i];
    int d = (i >> 2) / EPB;
    inv[node * 8 + d] = i;
}

// ---------------------------------------------------------------------------
// Per-edge: edge2r = bf16( relu( sum_k emb2[node_k] ) )   [E,128]
// ---------------------------------------------------------------------------
__global__ __launch_bounds__(256) void edge_sum(
    const short* __restrict__ emb2_b, const int* __restrict__ edge_nodes,
    short* __restrict__ edge2r)
{
    const int t = threadIdx.x;
    const int w = t >> 6, l = t & 63;
    const int e0 = blockIdx.x * 32 + w * 8;
    for (int it = 0; it < 8; ++it) {
        const int e = e0 + it;
        const int4 nd = *reinterpret_cast<const int4*>(edge_nodes + (size_t)e * KK);
        float s0 = bf2f(emb2_b[(size_t)nd.x * OUTD + l])
                 + bf2f(emb2_b[(size_t)nd.y * OUTD + l])
                 + bf2f(emb2_b[(size_t)nd.z * OUTD + l])
                 + bf2f(emb2_b[(size_t)nd.w * OUTD + l]);
        float s1 = bf2f(emb2_b[(size_t)nd.x * OUTD + 64 + l])
                 + bf2f(emb2_b[(size_t)nd.y * OUTD + 64 + l])
                 + bf2f(emb2_b[(size_t)nd.z * OUTD + 64 + l])
                 + bf2f(emb2_b[(size_t)nd.w * OUTD + 64 + l]);
        edge2r[(size_t)e * OUTD + l]      = f2bf(fmaxf(s0, 0.f));
        edge2r[(size_t)e * OUTD + 64 + l] = f2bf(fmaxf(s1, 0.f));
    }
}

// ---------------------------------------------------------------------------
// Per-node gather (one wave per node): recompute own tanh-term rows for the 8
// incident edges from L3-resident scaled_b, reduce, mat-vec vs LDS Wq, add
// gathered relu(edge2), write out. No atomics; out fully written.
// ---------------------------------------------------------------------------
__global__ __launch_bounds__(256) void node_out(
    const short* __restrict__ scaled_b, const short* __restrict__ edge2r,
    const int* __restrict__ inv, const int* __restrict__ edge_nodes,
    const float* __restrict__ Wq, const float* __restrict__ bq,
    float* __restrict__ out)
{
    __shared__ float s_wq[RANK * OUTD];   // 32 KB
    __shared__ float s_t[4][64];

    const int t = threadIdx.x;
    for (int i = t; i < RANK * OUTD / 4; i += 256)
        reinterpret_cast<float4*>(s_wq)[i] = reinterpret_cast<const float4*>(Wq)[i];
    __syncthreads();

    const int w = t >> 6, l = t & 63;
    const int n = blockIdx.x * 4 + w;

    float tsum = 0.f, s0 = 0.f, s1 = 0.f;
    #pragma unroll
    for (int d = 0; d < 8; ++d) {
        const int idx = inv[n * 8 + d];          // wave-uniform
        const int e = idx >> 2, k = idx & 3;
        const int4 nd = *reinterpret_cast<const int4*>(edge_nodes + (size_t)e * KK);
        float g0 = bf2f(scaled_b[(size_t)nd.x * RANK + l]);
        float g1 = bf2f(scaled_b[(size_t)nd.y * RANK + l]);
        float g2 = bf2f(scaled_b[(size_t)nd.z * RANK + l]);
        float g3 = bf2f(scaled_b[(size_t)nd.w * RANK + l]);
        float p = (k == 0) ? g1 * (g2 * g3)
                : (k == 1) ? g0 * (g2 * g3)
                : (k == 2) ? (g0 * g1) * g3
                :            (g0 * g1) * g2;
        tsum += tanhf(COEF * p);
        s0 += bf2f(edge2r[(size_t)e * OUTD + l]);
        s1 += bf2f(edge2r[(size_t)e * OUTD + 64 + l]);
    }
    s_t[w][l] = tsum;   // wave-local round-trip; compiler inserts lgkmcnt

    float q0 = 0.f, q1 = 0.f;
    #pragma unroll 8
    for (int r = 0; r < 64; ++r) {
        float tv = s_t[w][r];
        q0 = fmaf(tv, s_wq[r * OUTD + l], q0);
        q1 = fmaf(tv, s_wq[r * OUTD + 64 + l], q1);
    }
    // out = relu( (q + 8*bq + s) / 8 ) = relu( 0.125*(q+s) + bq )
    out[(size_t)n * OUTD + l]      = fmaxf(fmaf(0.125f, q0 + s0, bq[l]), 0.f);
    out[(size_t)n * OUTD + 64 + l] = fmaxf(fmaf(0.125f, q1 + s1, bq[64 + l]), 0.f);
}

extern "C" void kernel_launch(void* const* d_in, const int* in_sizes, int n_in,
                              void* d_out, int out_size, void* d_ws, size_t ws_size,
                              hipStream_t stream)
{
    const float* emb = (const float*)d_in[0];
    const float* Wp  = (const float*)d_in[1];
    const float* bp  = (const float*)d_in[2];
    const float* Wq  = (const float*)d_in[3];
    const float* bq  = (const float*)d_in[4];
    const float* W1  = (const float*)d_in[5];
    const float* b1  = (const float*)d_in[6];
    const float* W2  = (const float*)d_in[7];
    const float* b2  = (const float*)d_in[8];
    const int* edge_nodes = (const int*)d_in[9];
    float* out = (float*)d_out;

    // workspace layout (bytes): all 16B-aligned
    short* scaled_b = (short*)d_ws;                          // NN*64  bf16 = 12.8 MB
    short* emb2_b   = scaled_b + (size_t)NN * RANK;          // NN*128 bf16 = 25.6 MB
    short* edge2r   = emb2_b + (size_t)NN * OUTD;            // EE*128 bf16 = 51.2 MB
    int*   inv      = (int*)(edge2r + (size_t)EE * OUTD);    // NN*8 int    =  3.2 MB
    short* bWp      = (short*)(inv + (size_t)NN * DEG);      // 32 KB
    short* bW1      = bWp + 256 * 64;                        // 256 KB
    short* bW2      = bW1 + 256 * 512;                       // 128 KB

    pack_w<<<104, 256, 0, stream>>>(Wp, W1, W2, bWp, bW1, bW2);
    node_net_mfma<<<NN / 32, 256, 0, stream>>>(
        emb, (const short8*)bWp, bp, (const short8*)bW1, b1, (const short8*)bW2, b2,
        scaled_b, emb2_b);
    make_inv<<<EE * KK / 256, 256, 0, stream>>>(edge_nodes, inv);
    edge_sum<<<EE / 32, 256, 0, stream>>>(emb2_b, edge_nodes, edge2r);
    node_out<<<NN / 4, 256, 0, stream>>>(scaled_b, edge2r, inv, edge_nodes, Wq, bq, out);
}

// Round 4
// 477.621 us; speedup vs baseline: 5.1143x; 1.3195x over previous
//
#include <hip/hip_runtime.h>
#include <hip/hip_bf16.h>
#include <math.h>

#define NN   100000
#define EE   200000
#define KK   4
#define DEG  8
#define FEAT 256
#define RANK 64
#define HID  512
#define OUTD 128
#define EPB  25000   // edges per permutation block = NN/KK

// num = DEG^(1/K) = 8^0.25 ; coef = num / (K-1)! = num/6
#define NUMF  1.6817928305074290861f
#define COEF  0.28029880508457151435f

typedef __attribute__((ext_vector_type(8))) short short8;
typedef __attribute__((ext_vector_type(2))) short short2v;
typedef __attribute__((ext_vector_type(4))) float float4v;

__device__ __forceinline__ short f2bf(float x) {
    union { float f; unsigned u; } v; v.f = x;
    unsigned r = v.u + 0x7fff + ((v.u >> 16) & 1);   // RNE
    return (short)(r >> 16);
}
__device__ __forceinline__ float bf2f(short u) {
    union { unsigned u; float f; } v;
    v.u = ((unsigned)(unsigned short)u) << 16;
    return v.f;
}

// ---------------------------------------------------------------------------
// Pack Wp/W1/W2 (fp32 row-major [K x N]) into bf16 MFMA B-fragment order.
// ---------------------------------------------------------------------------
__global__ __launch_bounds__(256) void pack_w(
    const float* __restrict__ Wp, const float* __restrict__ W1,
    const float* __restrict__ W2,
    short* __restrict__ bWp, short* __restrict__ bW1, short* __restrict__ bW2)
{
    int g = blockIdx.x * 256 + threadIdx.x;   // 104 blocks * 256 = (32+256+128)*64
    int tile = g >> 6, l = g & 63;
    int lm = l & 15, lq = l >> 4;
    const float* src; short* dst; int N, kt, nt, tl;
    if (tile < 32)       { tl = tile;        nt = tl >> 3; kt = tl & 7;  src = Wp; dst = bWp; N = RANK; }
    else if (tile < 288) { tl = tile - 32;   nt = tl >> 3; kt = tl & 7;  src = W1; dst = bW1; N = HID;  }
    else                 { tl = tile - 288;  nt = tl >> 4; kt = tl & 15; src = W2; dst = bW2; N = OUTD; }
    short8 pk;
    #pragma unroll
    for (int j = 0; j < 8; ++j)
        pk[j] = f2bf(src[(size_t)(kt * 32 + lq * 8 + j) * N + nt * 16 + lm]);
    *reinterpret_cast<short8*>(dst + (size_t)(tl * 64 + l) * 8) = pk;
}

// ---------------------------------------------------------------------------
// Fused node network on MFMA (bf16 in, fp32 acc), bf16 outputs.
// ---------------------------------------------------------------------------
__global__ __launch_bounds__(256) void node_net_mfma(
    const float* __restrict__ emb,
    const short8* __restrict__ bWp, const float* __restrict__ bp,
    const short8* __restrict__ bW1, const float* __restrict__ b1,
    const short8* __restrict__ bW2, const float* __restrict__ b2,
    short* __restrict__ scaled_b, short* __restrict__ emb2_b)
{
    __shared__ short s_a[32][264];
    __shared__ short s_h[32][520];

    const int t = threadIdx.x;
    const int w = t >> 6, l = t & 63;
    const int lm = l & 15, lq = l >> 4;
    const int row0 = blockIdx.x * 32;

    for (int i = t; i < 32 * 32; i += 256) {
        int r = i >> 5, c8 = (i & 31) * 8;
        const float4* src = reinterpret_cast<const float4*>(emb + (size_t)(row0 + r) * FEAT + c8);
        float4 v0 = src[0], v1 = src[1];
        short8 pk;
        pk[0] = f2bf(v0.x); pk[1] = f2bf(v0.y); pk[2] = f2bf(v0.z); pk[3] = f2bf(v0.w);
        pk[4] = f2bf(v1.x); pk[5] = f2bf(v1.y); pk[6] = f2bf(v1.z); pk[7] = f2bf(v1.w);
        *reinterpret_cast<short8*>(&s_a[r][c8]) = pk;
    }
    __syncthreads();

    // ---- stage p: scaled ----
    {
        float4v acc0 = {0.f, 0.f, 0.f, 0.f}, acc1 = {0.f, 0.f, 0.f, 0.f};
        #pragma unroll
        for (int kt = 0; kt < 8; ++kt) {
            short8 a0 = *reinterpret_cast<const short8*>(&s_a[lm][kt * 32 + lq * 8]);
            short8 a1 = *reinterpret_cast<const short8*>(&s_a[16 + lm][kt * 32 + lq * 8]);
            short8 b  = bWp[(w * 8 + kt) * 64 + l];
            acc0 = __builtin_amdgcn_mfma_f32_16x16x32_bf16(a0, b, acc0, 0, 0, 0);
            acc1 = __builtin_amdgcn_mfma_f32_16x16x32_bf16(a1, b, acc1, 0, 0, 0);
        }
        const int col = w * 16 + lm;
        const float bpv = bp[col];
        #pragma unroll
        for (int rr = 0; rr < 4; ++rr) {
            scaled_b[(size_t)(row0 + lq * 4 + rr) * RANK + col]      = f2bf(NUMF * (acc0[rr] + bpv));
            scaled_b[(size_t)(row0 + 16 + lq * 4 + rr) * RANK + col] = f2bf(NUMF * (acc1[rr] + bpv));
        }
    }

    // ---- stage 1: hid = relu(emb@W1+b1) -> LDS bf16 ----
    {
        float4v acc[2][8];
        #pragma unroll
        for (int mt = 0; mt < 2; ++mt)
            #pragma unroll
            for (int n8 = 0; n8 < 8; ++n8)
                acc[mt][n8] = (float4v){0.f, 0.f, 0.f, 0.f};

        for (int kt = 0; kt < 8; ++kt) {
            short8 a0 = *reinterpret_cast<const short8*>(&s_a[lm][kt * 32 + lq * 8]);
            short8 a1 = *reinterpret_cast<const short8*>(&s_a[16 + lm][kt * 32 + lq * 8]);
            #pragma unroll
            for (int n8 = 0; n8 < 8; ++n8) {
                short8 b = bW1[((w * 8 + n8) * 8 + kt) * 64 + l];
                acc[0][n8] = __builtin_amdgcn_mfma_f32_16x16x32_bf16(a0, b, acc[0][n8], 0, 0, 0);
                acc[1][n8] = __builtin_amdgcn_mfma_f32_16x16x32_bf16(a1, b, acc[1][n8], 0, 0, 0);
            }
        }
        #pragma unroll
        for (int n8 = 0; n8 < 8; ++n8) {
            const int col = w * 128 + n8 * 16 + lm;
            const float bb = b1[col];
            #pragma unroll
            for (int mt = 0; mt < 2; ++mt)
                #pragma unroll
                for (int rr = 0; rr < 4; ++rr)
                    s_h[mt * 16 + lq * 4 + rr][col] = f2bf(fmaxf(acc[mt][n8][rr] + bb, 0.f));
        }
    }
    __syncthreads();

    // ---- stage 2: emb2 = hid @ W2 + b2 ----
    {
        float4v acc[2][2];
        #pragma unroll
        for (int mt = 0; mt < 2; ++mt)
            #pragma unroll
            for (int n2 = 0; n2 < 2; ++n2)
                acc[mt][n2] = (float4v){0.f, 0.f, 0.f, 0.f};

        for (int kt = 0; kt < 16; ++kt) {
            short8 a0 = *reinterpret_cast<const short8*>(&s_h[lm][kt * 32 + lq * 8]);
            short8 a1 = *reinterpret_cast<const short8*>(&s_h[16 + lm][kt * 32 + lq * 8]);
            #pragma unroll
            for (int n2 = 0; n2 < 2; ++n2) {
                short8 b = bW2[((w * 2 + n2) * 16 + kt) * 64 + l];
                acc[0][n2] = __builtin_amdgcn_mfma_f32_16x16x32_bf16(a0, b, acc[0][n2], 0, 0, 0);
                acc[1][n2] = __builtin_amdgcn_mfma_f32_16x16x32_bf16(a1, b, acc[1][n2], 0, 0, 0);
            }
        }
        #pragma unroll
        for (int n2 = 0; n2 < 2; ++n2) {
            const int col = w * 32 + n2 * 16 + lm;
            const float bb = b2[col];
            #pragma unroll
            for (int mt = 0; mt < 2; ++mt)
                #pragma unroll
                for (int rr = 0; rr < 4; ++rr)
                    emb2_b[(size_t)(row0 + mt * 16 + lq * 4 + rr) * OUTD + col] =
                        f2bf(acc[mt][n2][rr] + bb);
        }
    }
}

// ---------------------------------------------------------------------------
// Per-edge: edge2r = bf16( relu( sum_k emb2[node_k] ) ). Lane l owns cols
// {2l, 2l+1} -> all gathers/stores are 4B short2v.
// ---------------------------------------------------------------------------
__global__ __launch_bounds__(256) void edge_sum(
    const short* __restrict__ emb2_b, const int* __restrict__ edge_nodes,
    short* __restrict__ edge2r)
{
    const int t = threadIdx.x;
    const int w = t >> 6, l = t & 63;
    const int c = 2 * l;
    const int e0 = blockIdx.x * 32 + w * 8;
    #pragma unroll
    for (int it = 0; it < 8; ++it) {
        const int e = e0 + it;
        const int4 nd = *reinterpret_cast<const int4*>(edge_nodes + (size_t)e * KK);
        short2v u0 = *reinterpret_cast<const short2v*>(emb2_b + (size_t)nd.x * OUTD + c);
        short2v u1 = *reinterpret_cast<const short2v*>(emb2_b + (size_t)nd.y * OUTD + c);
        short2v u2 = *reinterpret_cast<const short2v*>(emb2_b + (size_t)nd.z * OUTD + c);
        short2v u3 = *reinterpret_cast<const short2v*>(emb2_b + (size_t)nd.w * OUTD + c);
        float s0 = bf2f(u0[0]) + bf2f(u1[0]) + bf2f(u2[0]) + bf2f(u3[0]);
        float s1 = bf2f(u0[1]) + bf2f(u1[1]) + bf2f(u2[1]) + bf2f(u3[1]);
        short2v o = { f2bf(fmaxf(s0, 0.f)), f2bf(fmaxf(s1, 0.f)) };
        *reinterpret_cast<short2v*>(edge2r + (size_t)e * OUTD + c) = o;
    }
}

// ---------------------------------------------------------------------------
// Neighbor table: for each (node n, perm block d) store the 3 OTHER members of
// its edge plus the edge id: nbr[n*8+d] = {o0, o1, o2, e}. One writer per cell.
// ---------------------------------------------------------------------------
__global__ __launch_bounds__(256) void make_nbr(
    const int* __restrict__ edge_nodes, int4* __restrict__ nbr)
{
    int i = blockIdx.x * 256 + threadIdx.x;          // < EE*KK = 800000
    int e = i >> 2, k = i & 3;
    const int4 nd = *reinterpret_cast<const int4*>(edge_nodes + (size_t)e * KK);
    int n  = (k == 0) ? nd.x : (k == 1) ? nd.y : (k == 2) ? nd.z : nd.w;
    int o0 = (k == 0) ? nd.y : nd.x;
    int o1 = (k <= 1) ? nd.z : nd.y;
    int o2 = (k <= 2) ? nd.w : nd.z;
    int d = e / EPB;
    nbr[(size_t)n * 8 + d] = make_int4(o0, o1, o2, e);
}

// ---------------------------------------------------------------------------
// Per-node (one wave per node): p_d = prod of 3 neighbor g-rows; tsum = sum
// tanh(COEF*p); q = tsum @ Wq (bf16 LDS); out = relu(0.125*(q + sum relu
// edge2) + bq). Lane l owns cols {2l, 2l+1}. Chain depth 2, ~40 loads/wave
// in flight. No atomics.
// ---------------------------------------------------------------------------
__global__ __launch_bounds__(256, 4) void node_out(
    const short* __restrict__ scaled_b, const short* __restrict__ edge2r,
    const int4* __restrict__ nbr,
    const float* __restrict__ Wq, const float* __restrict__ bq,
    float* __restrict__ out)
{
    __shared__ short s_wq[RANK * OUTD];   // bf16, 16 KB
    __shared__ float s_t[4][64];

    const int t = threadIdx.x;
    for (int i = t; i < RANK * OUTD / 4; i += 256) {
        float4 v = reinterpret_cast<const float4*>(Wq)[i];
        short2v p0 = { f2bf(v.x), f2bf(v.y) };
        short2v p1 = { f2bf(v.z), f2bf(v.w) };
        *reinterpret_cast<short2v*>(&s_wq[i * 4])     = p0;
        *reinterpret_cast<short2v*>(&s_wq[i * 4 + 2]) = p1;
    }
    __syncthreads();

    const int w = t >> 6, l = t & 63;
    const int c = 2 * l;
    const int n = blockIdx.x * 4 + w;

    int4 nb[8];
    #pragma unroll
    for (int d = 0; d < 8; ++d) nb[d] = nbr[(size_t)n * 8 + d];

    float tsum = 0.f, s0 = 0.f, s1 = 0.f;
    #pragma unroll
    for (int d = 0; d < 8; ++d) {
        float g1 = bf2f(scaled_b[(size_t)nb[d].x * RANK + l]);
        float g2 = bf2f(scaled_b[(size_t)nb[d].y * RANK + l]);
        float g3 = bf2f(scaled_b[(size_t)nb[d].z * RANK + l]);
        short2v u = *reinterpret_cast<const short2v*>(edge2r + (size_t)nb[d].w * OUTD + c);
        tsum += tanhf(COEF * (g1 * (g2 * g3)));
        s0 += bf2f(u[0]);
        s1 += bf2f(u[1]);
    }
    s_t[w][l] = tsum;   // wave-local round-trip (lgkmcnt handled by compiler)

    float q0 = 0.f, q1 = 0.f;
    #pragma unroll 8
    for (int r = 0; r < 64; ++r) {
        float tv = s_t[w][r];
        short2v wv = *reinterpret_cast<const short2v*>(&s_wq[r * OUTD + c]);
        q0 = fmaf(tv, bf2f(wv[0]), q0);
        q1 = fmaf(tv, bf2f(wv[1]), q1);
    }
    float2 bb = *reinterpret_cast<const float2*>(bq + c);
    float2 o;
    o.x = fmaxf(fmaf(0.125f, q0 + s0, bb.x), 0.f);
    o.y = fmaxf(fmaf(0.125f, q1 + s1, bb.y), 0.f);
    *reinterpret_cast<float2*>(out + (size_t)n * OUTD + c) = o;
}

extern "C" void kernel_launch(void* const* d_in, const int* in_sizes, int n_in,
                              void* d_out, int out_size, void* d_ws, size_t ws_size,
                              hipStream_t stream)
{
    const float* emb = (const float*)d_in[0];
    const float* Wp  = (const float*)d_in[1];
    const float* bp  = (const float*)d_in[2];
    const float* Wq  = (const float*)d_in[3];
    const float* bq  = (const float*)d_in[4];
    const float* W1  = (const float*)d_in[5];
    const float* b1  = (const float*)d_in[6];
    const float* W2  = (const float*)d_in[7];
    const float* b2  = (const float*)d_in[8];
    const int* edge_nodes = (const int*)d_in[9];
    float* out = (float*)d_out;

    // workspace layout; nbr ALIASES emb2_b (emb2_b dead after edge_sum).
    short* scaled_b = (short*)d_ws;                          // NN*64  bf16 = 12.8 MB
    short* emb2_b   = scaled_b + (size_t)NN * RANK;          // NN*128 bf16 = 25.6 MB
    short* edge2r   = emb2_b + (size_t)NN * OUTD;            // EE*128 bf16 = 51.2 MB
    short* bWp      = edge2r + (size_t)EE * OUTD;            // 32 KB
    short* bW1      = bWp + 256 * 64;                        // 256 KB
    short* bW2      = bW1 + 256 * 512;                       // 128 KB
    int4*  nbr      = (int4*)emb2_b;                         // NN*8 int4 = 12.8 MB (alias)

    pack_w<<<104, 256, 0, stream>>>(Wp, W1, W2, bWp, bW1, bW2);
    node_net_mfma<<<NN / 32, 256, 0, stream>>>(
        emb, (const short8*)bWp, bp, (const short8*)bW1, b1, (const short8*)bW2, b2,
        scaled_b, emb2_b);
    edge_sum<<<EE / 32, 256, 0, stream>>>(emb2_b, edge_nodes, edge2r);
    make_nbr<<<EE * KK / 256, 256, 0, stream>>>(edge_nodes, nbr);   // overwrites emb2_b
    node_out<<<NN / 4, 256, 0, stream>>>(scaled_b, edge2r, nbr, Wq, bq, out);
}

// Round 5
// 414.108 us; speedup vs baseline: 5.8987x; 1.1534x over previous
//
#include <hip/hip_runtime.h>
#include <hip/hip_bf16.h>
#include <math.h>

#define NN   100000
#define EE   200000
#define KK   4
#define DEG  8
#define FEAT 256
#define RANK 64
#define HID  512
#define OUTD 128
#define EPB  25000   // edges per permutation block = NN/KK

// num = DEG^(1/K) = 8^0.25 ; coef = num / (K-1)! = num/6
#define NUMF  1.6817928305074290861f
#define COEF  0.28029880508457151435f

typedef __attribute__((ext_vector_type(8))) short short8;
typedef __attribute__((ext_vector_type(4))) short short4v;
typedef __attribute__((ext_vector_type(2))) short short2v;
typedef __attribute__((ext_vector_type(4))) float float4v;

__device__ __forceinline__ short f2bf(float x) {
    union { float f; unsigned u; } v; v.f = x;
    unsigned r = v.u + 0x7fff + ((v.u >> 16) & 1);   // RNE
    return (short)(r >> 16);
}
__device__ __forceinline__ float bf2f(short u) {
    union { unsigned u; float f; } v;
    v.u = ((unsigned)(unsigned short)u) << 16;
    return v.f;
}

// ---------------------------------------------------------------------------
// Pack Wp/W1/W2 (fp32 row-major [K x N]) into bf16 MFMA B-fragment order.
// (Same data serves as A-operand of W^T in the swapped-operand MFMA.)
// ---------------------------------------------------------------------------
__global__ __launch_bounds__(256) void pack_w(
    const float* __restrict__ Wp, const float* __restrict__ W1,
    const float* __restrict__ W2,
    short* __restrict__ bWp, short* __restrict__ bW1, short* __restrict__ bW2)
{
    int g = blockIdx.x * 256 + threadIdx.x;   // 104 blocks * 256 = (32+256+128)*64
    int tile = g >> 6, l = g & 63;
    int lm = l & 15, lq = l >> 4;
    const float* src; short* dst; int N, kt, nt, tl;
    if (tile < 32)       { tl = tile;        nt = tl >> 3; kt = tl & 7;  src = Wp; dst = bWp; N = RANK; }
    else if (tile < 288) { tl = tile - 32;   nt = tl >> 3; kt = tl & 7;  src = W1; dst = bW1; N = HID;  }
    else                 { tl = tile - 288;  nt = tl >> 4; kt = tl & 15; src = W2; dst = bW2; N = OUTD; }
    short8 pk;
    #pragma unroll
    for (int j = 0; j < 8; ++j)
        pk[j] = f2bf(src[(size_t)(kt * 32 + lq * 8 + j) * N + nt * 16 + lm]);
    *reinterpret_cast<short8*>(dst + (size_t)(tl * 64 + l) * 8) = pk;
}

// ---------------------------------------------------------------------------
// Fused node network, v2: swapped-operand MFMA (D = (X@W)^T layout -> lane
// holds node=lane&15, 4 consecutive out-cols -> 8B vector epilogues), and
// stage1/stage2 chunk-fused through a small 128-col hid buffer.
// LDS = 16.9 KB (s_a) + 8.7 KB (s_h chunk) = 25.6 KB -> 6 blocks/CU.
// ---------------------------------------------------------------------------
__global__ __launch_bounds__(256) void node_net_mfma(
    const float* __restrict__ emb,
    const short8* __restrict__ bWp, const float* __restrict__ bp,
    const short8* __restrict__ bW1, const float* __restrict__ b1,
    const short8* __restrict__ bW2, const float* __restrict__ b2,
    short* __restrict__ scaled_b, short* __restrict__ emb2_b)
{
    __shared__ short s_a[32][264];   // 32 x 256 bf16, row stride 528 B (16B mult)
    __shared__ short s_h[32][136];   // 32 x 128 bf16 chunk, row stride 272 B

    const int t = threadIdx.x;
    const int w = t >> 6, l = t & 63;
    const int lm = l & 15, lq = l >> 4;
    const int row0 = blockIdx.x * 32;

    // ---- stage emb -> s_a (fp32 -> bf16) ----
    for (int i = t; i < 32 * 32; i += 256) {
        int r = i >> 5, c8 = (i & 31) * 8;
        const float4* src = reinterpret_cast<const float4*>(emb + (size_t)(row0 + r) * FEAT + c8);
        float4 v0 = src[0], v1 = src[1];
        short8 pk;
        pk[0] = f2bf(v0.x); pk[1] = f2bf(v0.y); pk[2] = f2bf(v0.z); pk[3] = f2bf(v0.w);
        pk[4] = f2bf(v1.x); pk[5] = f2bf(v1.y); pk[6] = f2bf(v1.z); pk[7] = f2bf(v1.w);
        *reinterpret_cast<short8*>(&s_a[r][c8]) = pk;
    }
    __syncthreads();

    // ---- stage p: scaled = NUM*(emb@Wp + bp); wave w owns out-cols [w*16,+16) ----
    {
        float4v acc0 = {0.f, 0.f, 0.f, 0.f}, acc1 = {0.f, 0.f, 0.f, 0.f};
        #pragma unroll
        for (int kt = 0; kt < 8; ++kt) {
            short8 e0 = *reinterpret_cast<const short8*>(&s_a[lm][kt * 32 + lq * 8]);
            short8 e1 = *reinterpret_cast<const short8*>(&s_a[16 + lm][kt * 32 + lq * 8]);
            short8 wv = bWp[(w * 8 + kt) * 64 + l];
            acc0 = __builtin_amdgcn_mfma_f32_16x16x32_bf16(wv, e0, acc0, 0, 0, 0);
            acc1 = __builtin_amdgcn_mfma_f32_16x16x32_bf16(wv, e1, acc1, 0, 0, 0);
        }
        const int cb = w * 16 + lq * 4;
        float4 bb = *reinterpret_cast<const float4*>(bp + cb);
        short4v o0 = { f2bf(NUMF * (acc0[0] + bb.x)), f2bf(NUMF * (acc0[1] + bb.y)),
                       f2bf(NUMF * (acc0[2] + bb.z)), f2bf(NUMF * (acc0[3] + bb.w)) };
        short4v o1 = { f2bf(NUMF * (acc1[0] + bb.x)), f2bf(NUMF * (acc1[1] + bb.y)),
                       f2bf(NUMF * (acc1[2] + bb.z)), f2bf(NUMF * (acc1[3] + bb.w)) };
        *reinterpret_cast<short4v*>(scaled_b + (size_t)(row0 + lm) * RANK + cb)      = o0;
        *reinterpret_cast<short4v*>(scaled_b + (size_t)(row0 + 16 + lm) * RANK + cb) = o1;
    }

    // ---- chunk-fused stage1/stage2: emb2 acc lives across 4 hid chunks ----
    float4v eacc[2][2];
    #pragma unroll
    for (int mt = 0; mt < 2; ++mt)
        #pragma unroll
        for (int n2 = 0; n2 < 2; ++n2)
            eacc[mt][n2] = (float4v){0.f, 0.f, 0.f, 0.f};

    for (int cc = 0; cc < 4; ++cc) {
        // stage-1 chunk: hid cols [cc*128, +128); wave w computes [w*32, +32)
        #pragma unroll
        for (int nt2 = 0; nt2 < 2; ++nt2) {
            float4v h0 = {0.f, 0.f, 0.f, 0.f}, h1 = {0.f, 0.f, 0.f, 0.f};
            const int gnt = cc * 8 + w * 2 + nt2;
            #pragma unroll
            for (int kt = 0; kt < 8; ++kt) {
                short8 e0 = *reinterpret_cast<const short8*>(&s_a[lm][kt * 32 + lq * 8]);
                short8 e1 = *reinterpret_cast<const short8*>(&s_a[16 + lm][kt * 32 + lq * 8]);
                short8 wv = bW1[(gnt * 8 + kt) * 64 + l];
                h0 = __builtin_amdgcn_mfma_f32_16x16x32_bf16(wv, e0, h0, 0, 0, 0);
                h1 = __builtin_amdgcn_mfma_f32_16x16x32_bf16(wv, e1, h1, 0, 0, 0);
            }
            const int col  = w * 32 + nt2 * 16 + lq * 4;   // chunk-local
            float4 bb = *reinterpret_cast<const float4*>(b1 + cc * 128 + col);
            short4v o0 = { f2bf(fmaxf(h0[0] + bb.x, 0.f)), f2bf(fmaxf(h0[1] + bb.y, 0.f)),
                           f2bf(fmaxf(h0[2] + bb.z, 0.f)), f2bf(fmaxf(h0[3] + bb.w, 0.f)) };
            short4v o1 = { f2bf(fmaxf(h1[0] + bb.x, 0.f)), f2bf(fmaxf(h1[1] + bb.y, 0.f)),
                           f2bf(fmaxf(h1[2] + bb.z, 0.f)), f2bf(fmaxf(h1[3] + bb.w, 0.f)) };
            *reinterpret_cast<short4v*>(&s_h[lm][col])      = o0;
            *reinterpret_cast<short4v*>(&s_h[16 + lm][col]) = o1;
        }
        __syncthreads();

        // stage-2 partial: accumulate this chunk's K into emb2
        #pragma unroll
        for (int kt2 = 0; kt2 < 4; ++kt2) {
            short8 hh0 = *reinterpret_cast<const short8*>(&s_h[lm][kt2 * 32 + lq * 8]);
            short8 hh1 = *reinterpret_cast<const short8*>(&s_h[16 + lm][kt2 * 32 + lq * 8]);
            const int gk = cc * 4 + kt2;
            #pragma unroll
            for (int n2 = 0; n2 < 2; ++n2) {
                short8 wv = bW2[((w * 2 + n2) * 16 + gk) * 64 + l];
                eacc[0][n2] = __builtin_amdgcn_mfma_f32_16x16x32_bf16(wv, hh0, eacc[0][n2], 0, 0, 0);
                eacc[1][n2] = __builtin_amdgcn_mfma_f32_16x16x32_bf16(wv, hh1, eacc[1][n2], 0, 0, 0);
            }
        }
        __syncthreads();
    }

    // ---- epilogue: emb2 = hid@W2 + b2; wave w owns cols [w*32,+32) ----
    #pragma unroll
    for (int n2 = 0; n2 < 2; ++n2) {
        const int col = w * 32 + n2 * 16 + lq * 4;
        float4 bb = *reinterpret_cast<const float4*>(b2 + col);
        #pragma unroll
        for (int mt = 0; mt < 2; ++mt) {
            short4v o = { f2bf(eacc[mt][n2][0] + bb.x), f2bf(eacc[mt][n2][1] + bb.y),
                          f2bf(eacc[mt][n2][2] + bb.z), f2bf(eacc[mt][n2][3] + bb.w) };
            *reinterpret_cast<short4v*>(emb2_b + (size_t)(row0 + mt * 16 + lm) * OUTD + col) = o;
        }
    }
}

// ---------------------------------------------------------------------------
// Per-edge: edge2r = bf16( relu( sum_k emb2[node_k] ) ). Lane l owns cols
// {2l, 2l+1} -> all gathers/stores are 4B short2v.
// ---------------------------------------------------------------------------
__global__ __launch_bounds__(256) void edge_sum(
    const short* __restrict__ emb2_b, const int* __restrict__ edge_nodes,
    short* __restrict__ edge2r)
{
    const int t = threadIdx.x;
    const int w = t >> 6, l = t & 63;
    const int c = 2 * l;
    const int e0 = blockIdx.x * 32 + w * 8;
    #pragma unroll
    for (int it = 0; it < 8; ++it) {
        const int e = e0 + it;
        const int4 nd = *reinterpret_cast<const int4*>(edge_nodes + (size_t)e * KK);
        short2v u0 = *reinterpret_cast<const short2v*>(emb2_b + (size_t)nd.x * OUTD + c);
        short2v u1 = *reinterpret_cast<const short2v*>(emb2_b + (size_t)nd.y * OUTD + c);
        short2v u2 = *reinterpret_cast<const short2v*>(emb2_b + (size_t)nd.z * OUTD + c);
        short2v u3 = *reinterpret_cast<const short2v*>(emb2_b + (size_t)nd.w * OUTD + c);
        float s0 = bf2f(u0[0]) + bf2f(u1[0]) + bf2f(u2[0]) + bf2f(u3[0]);
        float s1 = bf2f(u0[1]) + bf2f(u1[1]) + bf2f(u2[1]) + bf2f(u3[1]);
        short2v o = { f2bf(fmaxf(s0, 0.f)), f2bf(fmaxf(s1, 0.f)) };
        *reinterpret_cast<short2v*>(edge2r + (size_t)e * OUTD + c) = o;
    }
}

// ---------------------------------------------------------------------------
// Neighbor table: nbr[n*8+d] = {o0, o1, o2, e}. One writer per cell.
// ---------------------------------------------------------------------------
__global__ __launch_bounds__(256) void make_nbr(
    const int* __restrict__ edge_nodes, int4* __restrict__ nbr)
{
    int i = blockIdx.x * 256 + threadIdx.x;          // < EE*KK = 800000
    int e = i >> 2, k = i & 3;
    const int4 nd = *reinterpret_cast<const int4*>(edge_nodes + (size_t)e * KK);
    int n  = (k == 0) ? nd.x : (k == 1) ? nd.y : (k == 2) ? nd.z : nd.w;
    int o0 = (k == 0) ? nd.y : nd.x;
    int o1 = (k <= 1) ? nd.z : nd.y;
    int o2 = (k <= 2) ? nd.w : nd.z;
    int d = e / EPB;
    nbr[(size_t)n * 8 + d] = make_int4(o0, o1, o2, e);
}

// ---------------------------------------------------------------------------
// Per-node (one wave per node): tsum = sum_d tanh(COEF * prod g(neighbors));
// q = tsum @ Wq (bf16 LDS); out = relu(0.125*(q + sum relu edge2) + bq).
// ---------------------------------------------------------------------------
__global__ __launch_bounds__(256, 4) void node_out(
    const short* __restrict__ scaled_b, const short* __restrict__ edge2r,
    const int4* __restrict__ nbr,
    const float* __restrict__ Wq, const float* __restrict__ bq,
    float* __restrict__ out)
{
    __shared__ short s_wq[RANK * OUTD];   // bf16, 16 KB
    __shared__ float s_t[4][64];

    const int t = threadIdx.x;
    for (int i = t; i < RANK * OUTD / 4; i += 256) {
        float4 v = reinterpret_cast<const float4*>(Wq)[i];
        short2v p0 = { f2bf(v.x), f2bf(v.y) };
        short2v p1 = { f2bf(v.z), f2bf(v.w) };
        *reinterpret_cast<short2v*>(&s_wq[i * 4])     = p0;
        *reinterpret_cast<short2v*>(&s_wq[i * 4 + 2]) = p1;
    }
    __syncthreads();

    const int w = t >> 6, l = t & 63;
    const int c = 2 * l;
    const int n = blockIdx.x * 4 + w;

    int4 nb[8];
    #pragma unroll
    for (int d = 0; d < 8; ++d) nb[d] = nbr[(size_t)n * 8 + d];

    float tsum = 0.f, s0 = 0.f, s1 = 0.f;
    #pragma unroll
    for (int d = 0; d < 8; ++d) {
        float g1 = bf2f(scaled_b[(size_t)nb[d].x * RANK + l]);
        float g2 = bf2f(scaled_b[(size_t)nb[d].y * RANK + l]);
        float g3 = bf2f(scaled_b[(size_t)nb[d].z * RANK + l]);
        short2v u = *reinterpret_cast<const short2v*>(edge2r + (size_t)nb[d].w * OUTD + c);
        tsum += tanhf(COEF * (g1 * (g2 * g3)));
        s0 += bf2f(u[0]);
        s1 += bf2f(u[1]);
    }
    s_t[w][l] = tsum;   // wave-local round-trip (lgkmcnt handled by compiler)

    float q0 = 0.f, q1 = 0.f;
    #pragma unroll 8
    for (int r = 0; r < 64; ++r) {
        float tv = s_t[w][r];
        short2v wv = *reinterpret_cast<const short2v*>(&s_wq[r * OUTD + c]);
        q0 = fmaf(tv, bf2f(wv[0]), q0);
        q1 = fmaf(tv, bf2f(wv[1]), q1);
    }
    float2 bb = *reinterpret_cast<const float2*>(bq + c);
    float2 o;
    o.x = fmaxf(fmaf(0.125f, q0 + s0, bb.x), 0.f);
    o.y = fmaxf(fmaf(0.125f, q1 + s1, bb.y), 0.f);
    *reinterpret_cast<float2*>(out + (size_t)n * OUTD + c) = o;
}

extern "C" void kernel_launch(void* const* d_in, const int* in_sizes, int n_in,
                              void* d_out, int out_size, void* d_ws, size_t ws_size,
                              hipStream_t stream)
{
    const float* emb = (const float*)d_in[0];
    const float* Wp  = (const float*)d_in[1];
    const float* bp  = (const float*)d_in[2];
    const float* Wq  = (const float*)d_in[3];
    const float* bq  = (const float*)d_in[4];
    const float* W1  = (const float*)d_in[5];
    const float* b1  = (const float*)d_in[6];
    const float* W2  = (const float*)d_in[7];
    const float* b2  = (const float*)d_in[8];
    const int* edge_nodes = (const int*)d_in[9];
    float* out = (float*)d_out;

    // workspace layout; nbr ALIASES emb2_b (emb2_b dead after edge_sum).
    short* scaled_b = (short*)d_ws;                          // NN*64  bf16 = 12.8 MB
    short* emb2_b   = scaled_b + (size_t)NN * RANK;          // NN*128 bf16 = 25.6 MB
    short* edge2r   = emb2_b + (size_t)NN * OUTD;            // EE*128 bf16 = 51.2 MB
    short* bWp      = edge2r + (size_t)EE * OUTD;            // 32 KB
    short* bW1      = bWp + 256 * 64;                        // 256 KB
    short* bW2      = bW1 + 256 * 512;                       // 128 KB
    int4*  nbr      = (int4*)emb2_b;                         // NN*8 int4 = 12.8 MB (alias)

    pack_w<<<104, 256, 0, stream>>>(Wp, W1, W2, bWp, bW1, bW2);
    node_net_mfma<<<NN / 32, 256, 0, stream>>>(
        emb, (const short8*)bWp, bp, (const short8*)bW1, b1, (const short8*)bW2, b2,
        scaled_b, emb2_b);
    edge_sum<<<EE / 32, 256, 0, stream>>>(emb2_b, edge_nodes, edge2r);
    make_nbr<<<EE * KK / 256, 256, 0, stream>>>(edge_nodes, nbr);   // overwrites emb2_b
    node_out<<<NN / 4, 256, 0, stream>>>(scaled_b, edge2r, nbr, Wq, bq, out);
}

// Round 6
// 354.413 us; speedup vs baseline: 6.8923x; 1.1684x over previous
//
#include <hip/hip_runtime.h>
#include <hip/hip_bf16.h>
#include <math.h>

#define NN   100000
#define EE   200000
#define KK   4
#define DEG  8
#define FEAT 256
#define RANK 64
#define HID  512
#define OUTD 128
#define EPB  25000   // edges per permutation block = NN/KK

// num = DEG^(1/K) = 8^0.25 ; coef = num / (K-1)! = num/6
#define NUMF  1.6817928305074290861f
#define COEF  0.28029880508457151435f

typedef __attribute__((ext_vector_type(8))) short short8;
typedef __attribute__((ext_vector_type(4))) short short4v;
typedef __attribute__((ext_vector_type(2))) short short2v;
typedef __attribute__((ext_vector_type(4))) float float4v;

__device__ __forceinline__ short f2bf(float x) {
    union { float f; unsigned u; } v; v.f = x;
    unsigned r = v.u + 0x7fff + ((v.u >> 16) & 1);   // RNE
    return (short)(r >> 16);
}
__device__ __forceinline__ float bf2f(short u) {
    union { unsigned u; float f; } v;
    v.u = ((unsigned)(unsigned short)u) << 16;
    return v.f;
}
// fast tanh: 1 - 2/(e^{2y}+1); exact at +-inf, ~1ulp of v_exp_f32 elsewhere
__device__ __forceinline__ float fast_tanh(float y) {
    float ez = __expf(2.f * y);
    return 1.f - 2.f * __builtin_amdgcn_rcpf(ez + 1.f);
}

// ---------------------------------------------------------------------------
// Pack Wp/W1/W2/Wq (fp32 row-major [K x N]) into bf16 MFMA B-fragment order:
// tile (nt,kt) 32(k) x 16(n); lane l holds W[kt*32+(l>>4)*8+j][nt*16+(l&15)].
// ---------------------------------------------------------------------------
__global__ __launch_bounds__(256) void pack_w(
    const float* __restrict__ Wp, const float* __restrict__ W1,
    const float* __restrict__ W2, const float* __restrict__ Wq,
    short* __restrict__ bWp, short* __restrict__ bW1,
    short* __restrict__ bW2, short* __restrict__ bWq)
{
    int g = blockIdx.x * 256 + threadIdx.x;   // 108 blocks * 256 = (32+256+128+16)*64
    int tile = g >> 6, l = g & 63;
    int lm = l & 15, lq = l >> 4;
    const float* src; short* dst; int N, kt, nt, tl;
    if (tile < 32)       { tl = tile;        nt = tl >> 3; kt = tl & 7;  src = Wp; dst = bWp; N = RANK; }
    else if (tile < 288) { tl = tile - 32;   nt = tl >> 3; kt = tl & 7;  src = W1; dst = bW1; N = HID;  }
    else if (tile < 416) { tl = tile - 288;  nt = tl >> 4; kt = tl & 15; src = W2; dst = bW2; N = OUTD; }
    else                 { tl = tile - 416;  nt = tl >> 1; kt = tl & 1;  src = Wq; dst = bWq; N = OUTD; }
    short8 pk;
    #pragma unroll
    for (int j = 0; j < 8; ++j)
        pk[j] = f2bf(src[(size_t)(kt * 32 + lq * 8 + j) * N + nt * 16 + lm]);
    *reinterpret_cast<short8*>(dst + (size_t)(tl * 64 + l) * 8) = pk;
}

// ---------------------------------------------------------------------------
// Fused node network (swapped-operand MFMA, chunk-fused stage1/stage2).
// ---------------------------------------------------------------------------
__global__ __launch_bounds__(256) void node_net_mfma(
    const float* __restrict__ emb,
    const short8* __restrict__ bWp, const float* __restrict__ bp,
    const short8* __restrict__ bW1, const float* __restrict__ b1,
    const short8* __restrict__ bW2, const float* __restrict__ b2,
    short* __restrict__ scaled_b, short* __restrict__ emb2_b)
{
    __shared__ short s_a[32][264];   // 32 x 256 bf16, row stride 528 B
    __shared__ short s_h[32][136];   // 32 x 128 bf16 chunk

    const int t = threadIdx.x;
    const int w = t >> 6, l = t & 63;
    const int lm = l & 15, lq = l >> 4;
    const int row0 = blockIdx.x * 32;

    for (int i = t; i < 32 * 32; i += 256) {
        int r = i >> 5, c8 = (i & 31) * 8;
        const float4* src = reinterpret_cast<const float4*>(emb + (size_t)(row0 + r) * FEAT + c8);
        float4 v0 = src[0], v1 = src[1];
        short8 pk;
        pk[0] = f2bf(v0.x); pk[1] = f2bf(v0.y); pk[2] = f2bf(v0.z); pk[3] = f2bf(v0.w);
        pk[4] = f2bf(v1.x); pk[5] = f2bf(v1.y); pk[6] = f2bf(v1.z); pk[7] = f2bf(v1.w);
        *reinterpret_cast<short8*>(&s_a[r][c8]) = pk;
    }
    __syncthreads();

    // ---- stage p: scaled ----
    {
        float4v acc0 = {0.f, 0.f, 0.f, 0.f}, acc1 = {0.f, 0.f, 0.f, 0.f};
        #pragma unroll
        for (int kt = 0; kt < 8; ++kt) {
            short8 e0 = *reinterpret_cast<const short8*>(&s_a[lm][kt * 32 + lq * 8]);
            short8 e1 = *reinterpret_cast<const short8*>(&s_a[16 + lm][kt * 32 + lq * 8]);
            short8 wv = bWp[(w * 8 + kt) * 64 + l];
            acc0 = __builtin_amdgcn_mfma_f32_16x16x32_bf16(wv, e0, acc0, 0, 0, 0);
            acc1 = __builtin_amdgcn_mfma_f32_16x16x32_bf16(wv, e1, acc1, 0, 0, 0);
        }
        const int cb = w * 16 + lq * 4;
        float4 bb = *reinterpret_cast<const float4*>(bp + cb);
        short4v o0 = { f2bf(NUMF * (acc0[0] + bb.x)), f2bf(NUMF * (acc0[1] + bb.y)),
                       f2bf(NUMF * (acc0[2] + bb.z)), f2bf(NUMF * (acc0[3] + bb.w)) };
        short4v o1 = { f2bf(NUMF * (acc1[0] + bb.x)), f2bf(NUMF * (acc1[1] + bb.y)),
                       f2bf(NUMF * (acc1[2] + bb.z)), f2bf(NUMF * (acc1[3] + bb.w)) };
        *reinterpret_cast<short4v*>(scaled_b + (size_t)(row0 + lm) * RANK + cb)      = o0;
        *reinterpret_cast<short4v*>(scaled_b + (size_t)(row0 + 16 + lm) * RANK + cb) = o1;
    }

    // ---- chunk-fused stage1/stage2 ----
    float4v eacc[2][2];
    #pragma unroll
    for (int mt = 0; mt < 2; ++mt)
        #pragma unroll
        for (int n2 = 0; n2 < 2; ++n2)
            eacc[mt][n2] = (float4v){0.f, 0.f, 0.f, 0.f};

    for (int cc = 0; cc < 4; ++cc) {
        #pragma unroll
        for (int nt2 = 0; nt2 < 2; ++nt2) {
            float4v h0 = {0.f, 0.f, 0.f, 0.f}, h1 = {0.f, 0.f, 0.f, 0.f};
            const int gnt = cc * 8 + w * 2 + nt2;
            #pragma unroll
            for (int kt = 0; kt < 8; ++kt) {
                short8 e0 = *reinterpret_cast<const short8*>(&s_a[lm][kt * 32 + lq * 8]);
                short8 e1 = *reinterpret_cast<const short8*>(&s_a[16 + lm][kt * 32 + lq * 8]);
                short8 wv = bW1[(gnt * 8 + kt) * 64 + l];
                h0 = __builtin_amdgcn_mfma_f32_16x16x32_bf16(wv, e0, h0, 0, 0, 0);
                h1 = __builtin_amdgcn_mfma_f32_16x16x32_bf16(wv, e1, h1, 0, 0, 0);
            }
            const int col  = w * 32 + nt2 * 16 + lq * 4;   // chunk-local
            float4 bb = *reinterpret_cast<const float4*>(b1 + cc * 128 + col);
            short4v o0 = { f2bf(fmaxf(h0[0] + bb.x, 0.f)), f2bf(fmaxf(h0[1] + bb.y, 0.f)),
                           f2bf(fmaxf(h0[2] + bb.z, 0.f)), f2bf(fmaxf(h0[3] + bb.w, 0.f)) };
            short4v o1 = { f2bf(fmaxf(h1[0] + bb.x, 0.f)), f2bf(fmaxf(h1[1] + bb.y, 0.f)),
                           f2bf(fmaxf(h1[2] + bb.z, 0.f)), f2bf(fmaxf(h1[3] + bb.w, 0.f)) };
            *reinterpret_cast<short4v*>(&s_h[lm][col])      = o0;
            *reinterpret_cast<short4v*>(&s_h[16 + lm][col]) = o1;
        }
        __syncthreads();

        #pragma unroll
        for (int kt2 = 0; kt2 < 4; ++kt2) {
            short8 hh0 = *reinterpret_cast<const short8*>(&s_h[lm][kt2 * 32 + lq * 8]);
            short8 hh1 = *reinterpret_cast<const short8*>(&s_h[16 + lm][kt2 * 32 + lq * 8]);
            const int gk = cc * 4 + kt2;
            #pragma unroll
            for (int n2 = 0; n2 < 2; ++n2) {
                short8 wv = bW2[((w * 2 + n2) * 16 + gk) * 64 + l];
                eacc[0][n2] = __builtin_amdgcn_mfma_f32_16x16x32_bf16(wv, hh0, eacc[0][n2], 0, 0, 0);
                eacc[1][n2] = __builtin_amdgcn_mfma_f32_16x16x32_bf16(wv, hh1, eacc[1][n2], 0, 0, 0);
            }
        }
        __syncthreads();
    }

    #pragma unroll
    for (int n2 = 0; n2 < 2; ++n2) {
        const int col = w * 32 + n2 * 16 + lq * 4;
        float4 bb = *reinterpret_cast<const float4*>(b2 + col);
        #pragma unroll
        for (int mt = 0; mt < 2; ++mt) {
            short4v o = { f2bf(eacc[mt][n2][0] + bb.x), f2bf(eacc[mt][n2][1] + bb.y),
                          f2bf(eacc[mt][n2][2] + bb.z), f2bf(eacc[mt][n2][3] + bb.w) };
            *reinterpret_cast<short4v*>(emb2_b + (size_t)(row0 + mt * 16 + lm) * OUTD + col) = o;
        }
    }
}

// ---------------------------------------------------------------------------
// Per-edge: edge2r = bf16( relu( sum_k emb2[node_k] ) ).
// ---------------------------------------------------------------------------
__global__ __launch_bounds__(256) void edge_sum(
    const short* __restrict__ emb2_b, const int* __restrict__ edge_nodes,
    short* __restrict__ edge2r)
{
    const int t = threadIdx.x;
    const int w = t >> 6, l = t & 63;
    const int c = 2 * l;
    const int e0 = blockIdx.x * 32 + w * 8;
    #pragma unroll
    for (int it = 0; it < 8; ++it) {
        const int e = e0 + it;
        const int4 nd = *reinterpret_cast<const int4*>(edge_nodes + (size_t)e * KK);
        short2v u0 = *reinterpret_cast<const short2v*>(emb2_b + (size_t)nd.x * OUTD + c);
        short2v u1 = *reinterpret_cast<const short2v*>(emb2_b + (size_t)nd.y * OUTD + c);
        short2v u2 = *reinterpret_cast<const short2v*>(emb2_b + (size_t)nd.z * OUTD + c);
        short2v u3 = *reinterpret_cast<const short2v*>(emb2_b + (size_t)nd.w * OUTD + c);
        float s0 = bf2f(u0[0]) + bf2f(u1[0]) + bf2f(u2[0]) + bf2f(u3[0]);
        float s1 = bf2f(u0[1]) + bf2f(u1[1]) + bf2f(u2[1]) + bf2f(u3[1]);
        short2v o = { f2bf(fmaxf(s0, 0.f)), f2bf(fmaxf(s1, 0.f)) };
        *reinterpret_cast<short2v*>(edge2r + (size_t)e * OUTD + c) = o;
    }
}

// ---------------------------------------------------------------------------
// Neighbor table: nbr[n*8+d] = {o0, o1, o2, e}. One writer per cell.
// ---------------------------------------------------------------------------
__global__ __launch_bounds__(256) void make_nbr(
    const int* __restrict__ edge_nodes, int4* __restrict__ nbr)
{
    int i = blockIdx.x * 256 + threadIdx.x;          // < EE*KK = 800000
    int e = i >> 2, k = i & 3;
    const int4 nd = *reinterpret_cast<const int4*>(edge_nodes + (size_t)e * KK);
    int n  = (k == 0) ? nd.x : (k == 1) ? nd.y : (k == 2) ? nd.z : nd.w;
    int o0 = (k == 0) ? nd.y : nd.x;
    int o1 = (k <= 1) ? nd.z : nd.y;
    int o2 = (k <= 2) ? nd.w : nd.z;
    int d = e / EPB;
    nbr[(size_t)n * 8 + d] = make_int4(o0, o1, o2, e);
}

// ---------------------------------------------------------------------------
// Per-node, v3: 16 nodes/block. Gather phase (4 nodes/wave): tsum via fast
// tanh -> s_t bf16 (A-frag layout source), edge2 sums -> s_s fp32. Then one
// swapped-operand MFMA (bWq frag x s_t frag) does all 16 node mat-vecs; the
// C-layout gives lane=node, 4 consecutive cols -> float4 epilogue.
// ---------------------------------------------------------------------------
__global__ __launch_bounds__(256, 4) void node_out(
    const short* __restrict__ scaled_b, const short* __restrict__ edge2r,
    const int4* __restrict__ nbr,
    const short8* __restrict__ bWq, const float* __restrict__ bq,
    float* __restrict__ out)
{
    __shared__ short s_t[16][72];    // tsum bf16; pad 64->72: frag rows 4 banks apart
    __shared__ float s_s[16][132];   // edge2 sums fp32; pad 128->132

    const int t = threadIdx.x;
    const int w = t >> 6, l = t & 63;
    const int lm = l & 15, lq = l >> 4;
    const int c = 2 * l;
    const int nbase = blockIdx.x * 16;

    #pragma unroll
    for (int j = 0; j < 4; ++j) {
        const int n = nbase + w * 4 + j;
        int4 nb[8];
        #pragma unroll
        for (int d = 0; d < 8; ++d) nb[d] = nbr[(size_t)n * 8 + d];

        float tsum = 0.f, s0 = 0.f, s1 = 0.f;
        #pragma unroll
        for (int d = 0; d < 8; ++d) {
            float g1 = bf2f(scaled_b[(size_t)nb[d].x * RANK + l]);
            float g2 = bf2f(scaled_b[(size_t)nb[d].y * RANK + l]);
            float g3 = bf2f(scaled_b[(size_t)nb[d].z * RANK + l]);
            short2v u = *reinterpret_cast<const short2v*>(edge2r + (size_t)nb[d].w * OUTD + c);
            tsum += fast_tanh(COEF * (g1 * (g2 * g3)));
            s0 += bf2f(u[0]);
            s1 += bf2f(u[1]);
        }
        s_t[w * 4 + j][l] = f2bf(tsum);
        *reinterpret_cast<float2*>(&s_s[w * 4 + j][c]) = make_float2(s0, s1);
    }
    __syncthreads();

    // MFMA mat-vec: Q^T = Wq^T @ T^T ; wave w owns out cols [w*32, +32)
    float4v acc0 = {0.f, 0.f, 0.f, 0.f}, acc1 = {0.f, 0.f, 0.f, 0.f};
    #pragma unroll
    for (int kt = 0; kt < 2; ++kt) {
        short8 tf = *reinterpret_cast<const short8*>(&s_t[lm][kt * 32 + lq * 8]);
        short8 w0 = bWq[((w * 2 + 0) * 2 + kt) * 64 + l];
        short8 w1 = bWq[((w * 2 + 1) * 2 + kt) * 64 + l];
        acc0 = __builtin_amdgcn_mfma_f32_16x16x32_bf16(w0, tf, acc0, 0, 0, 0);
        acc1 = __builtin_amdgcn_mfma_f32_16x16x32_bf16(w1, tf, acc1, 0, 0, 0);
    }
    #pragma unroll
    for (int n2 = 0; n2 < 2; ++n2) {
        float4v a = n2 ? acc1 : acc0;
        const int col = w * 32 + n2 * 16 + lq * 4;
        float4 sv = *reinterpret_cast<const float4*>(&s_s[lm][col]);
        float4 bb = *reinterpret_cast<const float4*>(bq + col);
        float4 o;
        o.x = fmaxf(fmaf(0.125f, a[0] + sv.x, bb.x), 0.f);
        o.y = fmaxf(fmaf(0.125f, a[1] + sv.y, bb.y), 0.f);
        o.z = fmaxf(fmaf(0.125f, a[2] + sv.z, bb.z), 0.f);
        o.w = fmaxf(fmaf(0.125f, a[3] + sv.w, bb.w), 0.f);
        *reinterpret_cast<float4*>(out + (size_t)(nbase + lm) * OUTD + col) = o;
    }
}

extern "C" void kernel_launch(void* const* d_in, const int* in_sizes, int n_in,
                              void* d_out, int out_size, void* d_ws, size_t ws_size,
                              hipStream_t stream)
{
    const float* emb = (const float*)d_in[0];
    const float* Wp  = (const float*)d_in[1];
    const float* bp  = (const float*)d_in[2];
    const float* Wq  = (const float*)d_in[3];
    const float* bq  = (const float*)d_in[4];
    const float* W1  = (const float*)d_in[5];
    const float* b1  = (const float*)d_in[6];
    const float* W2  = (const float*)d_in[7];
    const float* b2  = (const float*)d_in[8];
    const int* edge_nodes = (const int*)d_in[9];
    float* out = (float*)d_out;

    // workspace layout; nbr ALIASES emb2_b (emb2_b dead after edge_sum).
    short* scaled_b = (short*)d_ws;                          // NN*64  bf16 = 12.8 MB
    short* emb2_b   = scaled_b + (size_t)NN * RANK;          // NN*128 bf16 = 25.6 MB
    short* edge2r   = emb2_b + (size_t)NN * OUTD;            // EE*128 bf16 = 51.2 MB
    short* bWp      = edge2r + (size_t)EE * OUTD;            // 32 KB
    short* bW1      = bWp + 256 * 64;                        // 256 KB
    short* bW2      = bW1 + 256 * 512;                       // 128 KB
    short* bWq      = bW2 + 512 * 128;                       // 16 KB
    int4*  nbr      = (int4*)emb2_b;                         // NN*8 int4 = 12.8 MB (alias)

    pack_w<<<108, 256, 0, stream>>>(Wp, W1, W2, Wq, bWp, bW1, bW2, bWq);
    node_net_mfma<<<NN / 32, 256, 0, stream>>>(
        emb, (const short8*)bWp, bp, (const short8*)bW1, b1, (const short8*)bW2, b2,
        scaled_b, emb2_b);
    edge_sum<<<EE / 32, 256, 0, stream>>>(emb2_b, edge_nodes, edge2r);
    make_nbr<<<EE * KK / 256, 256, 0, stream>>>(edge_nodes, nbr);   // overwrites emb2_b
    node_out<<<NN / 16, 256, 0, stream>>>(scaled_b, edge2r, nbr, (const short8*)bWq, bq, out);
}